// Round 1
// baseline (216.767 us; speedup 1.0000x reference)
//
#include <hip/hip_runtime.h>
#include <hip/hip_bf16.h>

#define D 64
#define NCH 8          // src chunks: ceil(100000/8)=12500 rows * 128 B = 1.6 MB << 4 MB XCD-L2
#define GPB 16         // groups (of 4 dst nodes) per block -> 64 nodes/block, 4 groups/wave

typedef __attribute__((ext_vector_type(8))) short bf16x8;
typedef __attribute__((ext_vector_type(4))) float f32x4;

// POD fragment: only trivially-copyable members (bf16 pairs kept as uint).
union Frag {
    bf16x8 v;
    unsigned int p[4];   // each = two packed bf16
    ushort u[8];
};

static __device__ __forceinline__ unsigned int bf16r(float f) {
    const unsigned int u = __float_as_uint(f);
    return (u + 0x7fffu + ((u >> 16) & 1u)) >> 16;   // RNE fp32->bf16
}

static __device__ __forceinline__ unsigned int pack2(float a, float b) {
    return bf16r(a) | (bf16r(b) << 16);              // [lo=a, hi=b]
}

// ---------------------------------------------------------------------------
// K1: Y = bf16( deg ⊙ (X @ W) ) — MFMA (16x16x32 bf16).
// W staged ONCE per block into LDS (coalesced float4 loads, RNE cvt,
// transposed Wt[c][k] bf16, stride 72 ushort = 144 B so every fragment
// slice is 16B-aligned), one barrier, then each wave builds its 8
// B-fragments with 8x ds_read_b128.
// Grid: 1 strip per wave (round 9: 768 blocks = 2 serial strips/wave at
// 12 waves/CU was latency-thin; ~6 blocks/CU doubles TLP on the
// load->pack->MFMA->store chain).
// ---------------------------------------------------------------------------
__global__ __launch_bounds__(256, 4)
void gcn_xw_mfma(const float* __restrict__ X, const float* __restrict__ W,
                 const float* __restrict__ deg, ushort* __restrict__ Y,
                 int n_nodes, int nstrips)
{
    __shared__ ushort Wt[64][72];      // Wt[c][k] = bf16(W[k][c])

    const int t    = threadIdx.x;
    const int lane = t & 63;
    const int q    = lane >> 4;        // quad 0..3
    const int r    = lane & 15;        // row-in-frag / col-in-frag

    // ---- cooperative W -> LDS (transposed, bf16); fully coalesced ----
    {
        const float4* __restrict__ W4 = (const float4*)W;
#pragma unroll
        for (int m = 0; m < 4; ++m) {
            const float4 v = W4[t + 256 * m];
            const int idx0 = 4 * (t + 256 * m);   // flat element idx of v.x
            const int k = idx0 >> 6;              // W row
            const int c = idx0 & 63;              // W col of v.x
            Wt[c + 0][k] = (ushort)bf16r(v.x);
            Wt[c + 1][k] = (ushort)bf16r(v.y);
            Wt[c + 2][k] = (ushort)bf16r(v.z);
            Wt[c + 3][k] = (ushort)bf16r(v.w);
        }
    }
    __syncthreads();

    // ---- B fragments: bf[ft][s].u[j] = bf16(W[32s+8q+j][16ft+r]) ----
    Frag bf[4][2];
#pragma unroll
    for (int ft = 0; ft < 4; ++ft)
#pragma unroll
        for (int s = 0; s < 2; ++s)
            bf[ft][s].v = *(const bf16x8*)&Wt[16 * ft + r][32 * s + 8 * q];

    const int wid = blockIdx.x * 4 + (t >> 6);
    const int nw  = gridDim.x * 4;

    for (int strip = wid; strip < nstrips; strip += nw) {
        const int n0 = strip * 16;
        const bool full = (n0 + 16 <= n_nodes);

        // ---- A fragments: af[s] holds X[n0 + r][32s + q*8 + j] ----
        Frag af[2];
        {
            const int row  = full ? (n0 + r) : min(n0 + r, n_nodes - 1);
            const float* __restrict__ xr = X + ((size_t)row << 6);
#pragma unroll
            for (int s = 0; s < 2; ++s) {
                const float4 f0 = *(const float4*)(xr + 32 * s + q * 8);
                const float4 f1 = *(const float4*)(xr + 32 * s + q * 8 + 4);
                af[s].p[0] = pack2(f0.x, f0.y);
                af[s].p[1] = pack2(f0.z, f0.w);
                af[s].p[2] = pack2(f1.x, f1.y);
                af[s].p[3] = pack2(f1.z, f1.w);
            }
        }

        // ---- 8 MFMA: acc[ft] = sum_s A_s * B[ft][s] ----
        f32x4 acc[4];
#pragma unroll
        for (int ft = 0; ft < 4; ++ft) {
            f32x4 z = {0.f, 0.f, 0.f, 0.f};
            acc[ft] = z;
        }
#pragma unroll
        for (int s = 0; s < 2; ++s)
#pragma unroll
            for (int ft = 0; ft < 4; ++ft)
                acc[ft] = __builtin_amdgcn_mfma_f32_16x16x32_bf16(
                              af[s].v, bf[ft][s].v, acc[ft], 0, 0, 0);

        // ---- epilogue: rows q*4+i, col r (+16*ft) ----
        if (full) {
            const float4 dn = *(const float4*)(deg + n0 + 4 * q);
#pragma unroll
            for (int i = 0; i < 4; ++i) {
                const int   node = n0 + 4 * q + i;
                const float d    = (i == 0) ? dn.x : (i == 1) ? dn.y
                                 : (i == 2) ? dn.z : dn.w;
                ushort* yr = Y + ((size_t)node << 6) + r;
#pragma unroll
                for (int ft = 0; ft < 4; ++ft)
                    yr[16 * ft] = (ushort)bf16r(acc[ft][i] * d);
            }
        } else {
#pragma unroll
            for (int i = 0; i < 4; ++i) {
                const int node = n0 + 4 * q + i;
                if (node < n_nodes) {
                    const float d = deg[node];
                    ushort* yr = Y + ((size_t)node << 6) + r;
#pragma unroll
                    for (int ft = 0; ft < 4; ++ft)
                        yr[16 * ft] = (ushort)bf16r(acc[ft][i] * d);
                }
            }
        }
    }
}

// ---------------------------------------------------------------------------
// K2 (round 10): src-chunk-phased gather. The 205 MB random full-line gather
// was served ~70% from Infinity Cache at ~5-6.6 TB/s effective (Y = 12.8 MB
// vs 4 MB per-XCD L2 -> ~31% L2 hit) => ~40 µs, BW-bound not latency-bound.
// Sweep src space in NCH=8 chunks (1.6 MB each, fits L2 with drift margin):
// chunk loop OUTERMOST so all co-resident blocks gather from the same small
// working set; per-block col window (4 KB) is L1/L2-resident across the 8
// re-scans. acc[4][4] fp32 stays in registers across all phases (static
// indexing only). Block owns GPB=16 contiguous groups (4/wave); grid 1563
// blocks, launch_bounds(256,6) caps VGPR<=85 so ~1536 blocks co-resident
// (phase coherence); 27 stragglers negligible. Every edge is processed in
// exactly one chunk -> bitwise-identical coverage, no sync needed.
// ---------------------------------------------------------------------------
__global__ __launch_bounds__(256, 6)
void gcn_gather_chunked(const ushort* __restrict__ Y, const int* __restrict__ rp,
                        const int* __restrict__ col, const float* __restrict__ deg,
                        float* __restrict__ out, int n_nodes)
{
    const int t    = threadIdx.x;
    const int lane = t & 63;
    const int w    = t >> 6;          // wave in block (0..3)
    const int s    = lane >> 4;       // node slot within group
    const int f    = lane & 15;       // feature chunk: floats [4f, 4f+4)

    const unsigned csz = (unsigned)((n_nodes + NCH - 1) / NCH);
    const int gbase = blockIdx.x * GPB + w * 4;   // this wave's 4 groups

    float a[4][4];                     // [k][feature] — static indexing only
#pragma unroll
    for (int k = 0; k < 4; ++k) { a[k][0] = 0.f; a[k][1] = 0.f; a[k][2] = 0.f; a[k][3] = 0.f; }

    for (int p = 0; p < NCH; ++p) {
        const unsigned lo = (unsigned)p * csz;
#pragma unroll
        for (int k = 0; k < 4; ++k) {
            const int  g     = gbase + k;
            const int  n     = g * 4 + s;
            const bool valid = (n < n_nodes);
            const int  rpn   = valid ? rp[n]     : 0;
            const int  rpe   = valid ? rp[n + 1] : 0;
            const int  dcnt  = rpe - rpn;

            float a0 = 0.f, a1 = 0.f, a2 = 0.f, a3 = 0.f;
            auto gth = [&](int id) {
                if ((unsigned)id - lo < csz) {
                    const uint2 u = *(const uint2*)(Y + ((size_t)id << 6) + (f << 2));
                    a0 += __uint_as_float(u.x << 16);
                    a1 += __uint_as_float(u.x & 0xffff0000u);
                    a2 += __uint_as_float(u.y << 16);
                    a3 += __uint_as_float(u.y & 0xffff0000u);
                }
            };

            const bool ok = !valid || (dcnt == 16 && (rpn & 3) == 0);
            if (__ballot(ok) == ~0ull) {
#pragma unroll
                for (int b4 = 0; b4 < 4; ++b4) {
                    const int4 c = *(const int4*)(col + rpn + 4 * b4);
                    gth(c.x); gth(c.y); gth(c.z); gth(c.w);
                }
            } else if (valid) {
                for (int e = rpn; e < rpe; ++e) gth(col[e]);
            }
            a[k][0] += a0; a[k][1] += a1; a[k][2] += a2; a[k][3] += a3;
        }
    }

    // epilogue: scale by deg, one float4 store per (group, lane)
#pragma unroll
    for (int k = 0; k < 4; ++k) {
        const int g = gbase + k;
        const int n = g * 4 + s;
        if (n < n_nodes) {
            const float dn = deg[n];
            float4 v;
            v.x = a[k][0] * dn; v.y = a[k][1] * dn;
            v.z = a[k][2] * dn; v.w = a[k][3] * dn;
            *(float4*)(out + ((size_t)n << 6) + (f << 2)) = v;
        }
    }
}

// ---------------------------------------------------------------------------
// Fallback (ws too small): fused fp32 kernel.
// ---------------------------------------------------------------------------
static __device__ __forceinline__ float bcast_f(float v, int l) {
    return __uint_as_float(__builtin_amdgcn_readlane(__float_as_uint(v), l));
}

__global__ __launch_bounds__(256, 4)
void gcn_fused_kernel(const float* __restrict__ X, const float* __restrict__ W,
                      const int* __restrict__ rp, const int* __restrict__ col,
                      const float* __restrict__ deg, float* __restrict__ out,
                      int n_nodes)
{
    const int lane   = threadIdx.x & 63;
    const int gwave  = (int)((blockIdx.x * blockDim.x + threadIdx.x) >> 6);
    const int nwaves = (int)((gridDim.x * blockDim.x) >> 6);

    for (int node = gwave; node < n_nodes; node += nwaves) {
        const int start = rp[node];
        const int end   = rp[node + 1];
        const float di  = deg[node];
        float h = 0.f;

        for (int e0 = start; e0 < end; e0 += 64) {
            const int cnt = min(64, end - e0);
            int   s_  = (lane < cnt) ? col[e0 + lane] : 0;
            float nm_ = (lane < cnt) ? di * deg[s_] : 0.f;
            for (int j = 0; j < cnt; ++j) {
                const int   sj = __builtin_amdgcn_readlane(s_, j);
                const float nj = bcast_f(nm_, j);
                h = fmaf(nj, X[(size_t)sj * D + lane], h);
            }
        }

        float c0 = 0.f, c1 = 0.f, c2 = 0.f, c3 = 0.f;
#pragma unroll
        for (int l = 0; l < D; l += 4) {
            c0 = fmaf(bcast_f(h, l + 0), W[(l + 0) * D + lane], c0);
            c1 = fmaf(bcast_f(h, l + 1), W[(l + 1) * D + lane], c1);
            c2 = fmaf(bcast_f(h, l + 2), W[(l + 2) * D + lane], c2);
            c3 = fmaf(bcast_f(h, l + 3), W[(l + 3) * D + lane], c3);
        }
        out[(size_t)node * D + lane] = (c0 + c1) + (c2 + c3);
    }
}

extern "C" void kernel_launch(void* const* d_in, const int* in_sizes, int n_in,
                              void* d_out, int out_size, void* d_ws, size_t ws_size,
                              hipStream_t stream) {
    const float* X   = (const float*)d_in[0];
    const float* W   = (const float*)d_in[1];
    const int*   rp  = (const int*)d_in[2];
    const int*   col = (const int*)d_in[3];
    const float* deg = (const float*)d_in[4];
    float* out = (float*)d_out;

    const int n_nodes = in_sizes[4];   // degrees: one per node
    const size_t y_bytes = (size_t)n_nodes * D * sizeof(ushort);

    if (ws_size >= y_bytes) {
        ushort* Y = (ushort*)d_ws;
        const int nstrips = (n_nodes + 15) / 16;
        int nb1 = (nstrips + 3) / 4;           // 1 strip per wave
        if (nb1 > 4096) nb1 = 4096;
        gcn_xw_mfma<<<nb1, 256, 0, stream>>>(X, W, deg, Y, n_nodes, nstrips);

        const int ngroups = (n_nodes + 3) >> 2;
        const int nb2 = (ngroups + GPB - 1) / GPB;   // 1563 for N=100000
        gcn_gather_chunked<<<nb2, 256, 0, stream>>>(Y, rp, col, deg, out, n_nodes);
    } else {
        gcn_fused_kernel<<<1024, 256, 0, stream>>>(X, W, rp, col, deg, out, n_nodes);
    }
}

// Round 2
// 146.113 us; speedup vs baseline: 1.4836x; 1.4836x over previous
//
#include <hip/hip_runtime.h>
#include <hip/hip_bf16.h>

#define D 64

typedef __attribute__((ext_vector_type(8))) short bf16x8;
typedef __attribute__((ext_vector_type(4))) float f32x4;

// POD fragment: only trivially-copyable members (bf16 pairs kept as uint).
union Frag {
    bf16x8 v;
    unsigned int p[4];   // each = two packed bf16
    ushort u[8];
};

static __device__ __forceinline__ unsigned int bf16r(float f) {
    const unsigned int u = __float_as_uint(f);
    return (u + 0x7fffu + ((u >> 16) & 1u)) >> 16;   // RNE fp32->bf16
}

static __device__ __forceinline__ unsigned int pack2(float a, float b) {
    return bf16r(a) | (bf16r(b) << 16);              // [lo=a, hi=b]
}

// ---------------------------------------------------------------------------
// K1: Y = bf16( deg ⊙ (X @ W) ) — MFMA (16x16x32 bf16).
// W staged ONCE per block into LDS (coalesced float4 loads, RNE cvt,
// transposed Wt[c][k] bf16, stride 72 ushort = 144 B so every fragment
// slice is 16B-aligned), one barrier, then each wave builds its 8
// B-fragments with 8x ds_read_b128.
// Round 2: __launch_bounds__(256,6) + 1536 blocks — all co-resident
// (6/CU = 24 waves/CU), ~1 strip/wave. Round 1's 1563 blocks under
// (256,4) ran as two half-empty batches (only 1024 resident) and
// regressed; round 0's 768 blocks left a serial 2-strip dependent chain
// per wave at 12 waves/CU. K1 is latency-thin (BW floor ~6.4 µs).
// ---------------------------------------------------------------------------
__global__ __launch_bounds__(256, 6)
void gcn_xw_mfma(const float* __restrict__ X, const float* __restrict__ W,
                 const float* __restrict__ deg, ushort* __restrict__ Y,
                 int n_nodes, int nstrips)
{
    __shared__ ushort Wt[64][72];      // Wt[c][k] = bf16(W[k][c])

    const int t    = threadIdx.x;
    const int lane = t & 63;
    const int q    = lane >> 4;        // quad 0..3
    const int r    = lane & 15;        // row-in-frag / col-in-frag

    // ---- cooperative W -> LDS (transposed, bf16); fully coalesced ----
    {
        const float4* __restrict__ W4 = (const float4*)W;
#pragma unroll
        for (int m = 0; m < 4; ++m) {
            const float4 v = W4[t + 256 * m];
            const int idx0 = 4 * (t + 256 * m);   // flat element idx of v.x
            const int k = idx0 >> 6;              // W row
            const int c = idx0 & 63;              // W col of v.x
            Wt[c + 0][k] = (ushort)bf16r(v.x);
            Wt[c + 1][k] = (ushort)bf16r(v.y);
            Wt[c + 2][k] = (ushort)bf16r(v.z);
            Wt[c + 3][k] = (ushort)bf16r(v.w);
        }
    }
    __syncthreads();

    // ---- B fragments: bf[ft][s].u[j] = bf16(W[32s+8q+j][16ft+r]) ----
    Frag bf[4][2];
#pragma unroll
    for (int ft = 0; ft < 4; ++ft)
#pragma unroll
        for (int s = 0; s < 2; ++s)
            bf[ft][s].v = *(const bf16x8*)&Wt[16 * ft + r][32 * s + 8 * q];

    const int wid = blockIdx.x * 4 + (t >> 6);
    const int nw  = gridDim.x * 4;

    for (int strip = wid; strip < nstrips; strip += nw) {
        const int n0 = strip * 16;
        const bool full = (n0 + 16 <= n_nodes);

        // ---- A fragments: af[s] holds X[n0 + r][32s + q*8 + j] ----
        Frag af[2];
        {
            const int row  = full ? (n0 + r) : min(n0 + r, n_nodes - 1);
            const float* __restrict__ xr = X + ((size_t)row << 6);
#pragma unroll
            for (int s = 0; s < 2; ++s) {
                const float4 f0 = *(const float4*)(xr + 32 * s + q * 8);
                const float4 f1 = *(const float4*)(xr + 32 * s + q * 8 + 4);
                af[s].p[0] = pack2(f0.x, f0.y);
                af[s].p[1] = pack2(f0.z, f0.w);
                af[s].p[2] = pack2(f1.x, f1.y);
                af[s].p[3] = pack2(f1.z, f1.w);
            }
        }

        // ---- 8 MFMA: acc[ft] = sum_s A_s * B[ft][s] ----
        f32x4 acc[4];
#pragma unroll
        for (int ft = 0; ft < 4; ++ft) {
            f32x4 z = {0.f, 0.f, 0.f, 0.f};
            acc[ft] = z;
        }
#pragma unroll
        for (int s = 0; s < 2; ++s)
#pragma unroll
            for (int ft = 0; ft < 4; ++ft)
                acc[ft] = __builtin_amdgcn_mfma_f32_16x16x32_bf16(
                              af[s].v, bf[ft][s].v, acc[ft], 0, 0, 0);

        // ---- epilogue: rows q*4+i, col r (+16*ft) ----
        if (full) {
            const float4 dn = *(const float4*)(deg + n0 + 4 * q);
#pragma unroll
            for (int i = 0; i < 4; ++i) {
                const int   node = n0 + 4 * q + i;
                const float d    = (i == 0) ? dn.x : (i == 1) ? dn.y
                                 : (i == 2) ? dn.z : dn.w;
                ushort* yr = Y + ((size_t)node << 6) + r;
#pragma unroll
                for (int ft = 0; ft < 4; ++ft)
                    yr[16 * ft] = (ushort)bf16r(acc[ft][i] * d);
            }
        } else {
#pragma unroll
            for (int i = 0; i < 4; ++i) {
                const int node = n0 + 4 * q + i;
                if (node < n_nodes) {
                    const float d = deg[node];
                    ushort* yr = Y + ((size_t)node << 6) + r;
#pragma unroll
                    for (int ft = 0; ft < 4; ++ft)
                        yr[16 * ft] = (ushort)bf16r(acc[ft][i] * d);
                }
            }
        }
    }
}

// ---------------------------------------------------------------------------
// K2: out[i][:] = deg[i] * sum_e Y[col[e]][:]  — 4 nodes per wave, no
// cross-lane ops. lane = (slot s=lane>>4 -> node, chunk f=lane&15 ->
// features [4f,4f+4)). Each lane owns its node's 16 edge indices (4 dwordx4
// loads), 16 independent dwordx2 row loads, accumulates 4 fp32, stores one
// float4. ~205 MB random full-line gather (each 128B line = one fully-used
// Y row) from L2/LLC.
// Round 2: __launch_bounds__(256,8) — VGPR use ~40 fits the 64 cap, so
// 2048 blocks = exactly 8/CU, 32 waves/CU, double the TLP vs (256,4).
// (Round 1's chunk-phased variant was issue-bound at 133 µs: per-edge
// predication multiplied vmem instruction count 8x and broke MLP.)
// ---------------------------------------------------------------------------
__global__ __launch_bounds__(256, 8)
void gcn_gather4(const ushort* __restrict__ Y, const int* __restrict__ rp,
                 const int* __restrict__ col, const float* __restrict__ deg,
                 float* __restrict__ out, int n_nodes)
{
    const int lane   = threadIdx.x & 63;
    const int s      = lane >> 4;
    const int f      = lane & 15;
    const int gwave  = (int)((blockIdx.x * blockDim.x + threadIdx.x) >> 6);
    const int nwaves = (int)((gridDim.x * blockDim.x) >> 6);
    const int ngroups = (n_nodes + 3) >> 2;

    for (int g = gwave; g < ngroups; g += nwaves) {
        const int  n     = g * 4 + s;
        const bool valid = (n < n_nodes);
        const int  rpn   = valid ? rp[n]     : 0;
        const int  rpe   = valid ? rp[n + 1] : 0;
        const int  dcnt  = rpe - rpn;

        const bool ok = !valid || (dcnt == 16 && (rpn & 3) == 0);
        if (__ballot(ok) == ~0ull) {
            int idx[16];
            *(int4*)(idx + 0)  = *(const int4*)(col + rpn + 0);
            *(int4*)(idx + 4)  = *(const int4*)(col + rpn + 4);
            *(int4*)(idx + 8)  = *(const int4*)(col + rpn + 8);
            *(int4*)(idx + 12) = *(const int4*)(col + rpn + 12);

            float a0 = 0.f, a1 = 0.f, a2 = 0.f, a3 = 0.f;
#pragma unroll
            for (int j = 0; j < 16; ++j) {
                const uint2 u = *(const uint2*)(Y + ((size_t)idx[j] << 6) + (f << 2));
                a0 += __uint_as_float(u.x << 16);
                a1 += __uint_as_float(u.x & 0xffff0000u);
                a2 += __uint_as_float(u.y << 16);
                a3 += __uint_as_float(u.y & 0xffff0000u);
            }
            if (valid) {
                const float dn = deg[n];
                float4 v;
                v.x = a0 * dn; v.y = a1 * dn; v.z = a2 * dn; v.w = a3 * dn;
                *(float4*)(out + (size_t)n * D + f * 4) = v;
            }
        } else if (valid) {
            float a0 = 0.f, a1 = 0.f, a2 = 0.f, a3 = 0.f;
            for (int e = rpn; e < rpe; ++e) {
                const int sj = col[e];
                const uint2 u = *(const uint2*)(Y + ((size_t)sj << 6) + (f << 2));
                a0 += __uint_as_float(u.x << 16);
                a1 += __uint_as_float(u.x & 0xffff0000u);
                a2 += __uint_as_float(u.y << 16);
                a3 += __uint_as_float(u.y & 0xffff0000u);
            }
            const float dn = deg[n];
            float4 v;
            v.x = a0 * dn; v.y = a1 * dn; v.z = a2 * dn; v.w = a3 * dn;
            *(float4*)(out + (size_t)n * D + f * 4) = v;
        }
    }
}

// ---------------------------------------------------------------------------
// Fallback (ws too small): fused fp32 kernel.
// ---------------------------------------------------------------------------
static __device__ __forceinline__ float bcast_f(float v, int l) {
    return __uint_as_float(__builtin_amdgcn_readlane(__float_as_uint(v), l));
}

__global__ __launch_bounds__(256, 4)
void gcn_fused_kernel(const float* __restrict__ X, const float* __restrict__ W,
                      const int* __restrict__ rp, const int* __restrict__ col,
                      const float* __restrict__ deg, float* __restrict__ out,
                      int n_nodes)
{
    const int lane   = threadIdx.x & 63;
    const int gwave  = (int)((blockIdx.x * blockDim.x + threadIdx.x) >> 6);
    const int nwaves = (int)((gridDim.x * blockDim.x) >> 6);

    for (int node = gwave; node < n_nodes; node += nwaves) {
        const int start = rp[node];
        const int end   = rp[node + 1];
        const float di  = deg[node];
        float h = 0.f;

        for (int e0 = start; e0 < end; e0 += 64) {
            const int cnt = min(64, end - e0);
            int   s_  = (lane < cnt) ? col[e0 + lane] : 0;
            float nm_ = (lane < cnt) ? di * deg[s_] : 0.f;
            for (int j = 0; j < cnt; ++j) {
                const int   sj = __builtin_amdgcn_readlane(s_, j);
                const float nj = bcast_f(nm_, j);
                h = fmaf(nj, X[(size_t)sj * D + lane], h);
            }
        }

        float c0 = 0.f, c1 = 0.f, c2 = 0.f, c3 = 0.f;
#pragma unroll
        for (int l = 0; l < D; l += 4) {
            c0 = fmaf(bcast_f(h, l + 0), W[(l + 0) * D + lane], c0);
            c1 = fmaf(bcast_f(h, l + 1), W[(l + 1) * D + lane], c1);
            c2 = fmaf(bcast_f(h, l + 2), W[(l + 2) * D + lane], c2);
            c3 = fmaf(bcast_f(h, l + 3), W[(l + 3) * D + lane], c3);
        }
        out[(size_t)node * D + lane] = (c0 + c1) + (c2 + c3);
    }
}

extern "C" void kernel_launch(void* const* d_in, const int* in_sizes, int n_in,
                              void* d_out, int out_size, void* d_ws, size_t ws_size,
                              hipStream_t stream) {
    const float* X   = (const float*)d_in[0];
    const float* W   = (const float*)d_in[1];
    const int*   rp  = (const int*)d_in[2];
    const int*   col = (const int*)d_in[3];
    const float* deg = (const float*)d_in[4];
    float* out = (float*)d_out;

    const int n_nodes = in_sizes[4];   // degrees: one per node
    const size_t y_bytes = (size_t)n_nodes * D * sizeof(ushort);

    if (ws_size >= y_bytes) {
        ushort* Y = (ushort*)d_ws;
        const int nstrips = (n_nodes + 15) / 16;
        // 1536 blocks = 6/CU (launch_bounds(256,6)), all co-resident,
        // ~1 strip per wave; latency-thin kernel wants max TLP.
        gcn_xw_mfma<<<1536, 256, 0, stream>>>(X, W, deg, Y, n_nodes, nstrips);
        // 2048 blocks = exactly 8/CU at launch_bounds(256,8): 32 waves/CU.
        gcn_gather4<<<2048, 256, 0, stream>>>(Y, rp, col, deg, out, n_nodes);
    } else {
        gcn_fused_kernel<<<1024, 256, 0, stream>>>(X, W, rp, col, deg, out, n_nodes);
    }
}

// Round 4
// 144.515 us; speedup vs baseline: 1.5000x; 1.0111x over previous
//
#include <hip/hip_runtime.h>
#include <hip/hip_bf16.h>

#define D 64

typedef __attribute__((ext_vector_type(8))) short bf16x8;
typedef __attribute__((ext_vector_type(4))) float f32x4;

// POD fragment: only trivially-copyable members (bf16 pairs kept as uint).
union Frag {
    bf16x8 v;
    unsigned int p[4];   // each = two packed bf16
    ushort u[8];
};

static __device__ __forceinline__ unsigned int bf16r(float f) {
    const unsigned int u = __float_as_uint(f);
    return (u + 0x7fffu + ((u >> 16) & 1u)) >> 16;   // RNE fp32->bf16
}

static __device__ __forceinline__ unsigned int pack2(float a, float b) {
    return bf16r(a) | (bf16r(b) << 16);              // [lo=a, hi=b]
}

// ---------------------------------------------------------------------------
// K1: Y = bf16( deg ⊙ (X @ W) ) — MFMA (16x16x32 bf16).
// ROUND-0 PROVEN CONFIG: 768 blocks, __launch_bounds__(256,4).
// (Round 2's (256,6) cap regressed K1 ~9->37 us — VGPR cap broke the
// pipeline. Do not touch the launch config.)
// W staged ONCE per block into LDS (coalesced float4 loads, RNE cvt,
// transposed Wt[c][k] bf16, stride 72 ushort = 144 B so every fragment
// slice is 16B-aligned), one barrier, then each wave builds its 8
// B-fragments with 8x ds_read_b128. Strip loop: 4 float4 X loads/lane in
// A-fragment layout, cvt, 8 MFMA, deg-scale, round, 16 ushort stores.
// ---------------------------------------------------------------------------
__global__ __launch_bounds__(256, 4)
void gcn_xw_mfma(const float* __restrict__ X, const float* __restrict__ W,
                 const float* __restrict__ deg, ushort* __restrict__ Y,
                 int n_nodes, int nstrips)
{
    __shared__ ushort Wt[64][72];      // Wt[c][k] = bf16(W[k][c])

    const int t    = threadIdx.x;
    const int lane = t & 63;
    const int q    = lane >> 4;        // quad 0..3
    const int r    = lane & 15;        // row-in-frag / col-in-frag

    // ---- cooperative W -> LDS (transposed, bf16); fully coalesced ----
    {
        const float4* __restrict__ W4 = (const float4*)W;
#pragma unroll
        for (int m = 0; m < 4; ++m) {
            const float4 v = W4[t + 256 * m];
            const int idx0 = 4 * (t + 256 * m);   // flat element idx of v.x
            const int k = idx0 >> 6;              // W row
            const int c = idx0 & 63;              // W col of v.x
            Wt[c + 0][k] = (ushort)bf16r(v.x);
            Wt[c + 1][k] = (ushort)bf16r(v.y);
            Wt[c + 2][k] = (ushort)bf16r(v.z);
            Wt[c + 3][k] = (ushort)bf16r(v.w);
        }
    }
    __syncthreads();

    // ---- B fragments: bf[ft][s].u[j] = bf16(W[32s+8q+j][16ft+r]) ----
    Frag bf[4][2];
#pragma unroll
    for (int ft = 0; ft < 4; ++ft)
#pragma unroll
        for (int s = 0; s < 2; ++s)
            bf[ft][s].v = *(const bf16x8*)&Wt[16 * ft + r][32 * s + 8 * q];

    const int wid = blockIdx.x * 4 + (t >> 6);
    const int nw  = gridDim.x * 4;

    for (int strip = wid; strip < nstrips; strip += nw) {
        const int n0 = strip * 16;
        const bool full = (n0 + 16 <= n_nodes);

        // ---- A fragments: af[s] holds X[n0 + r][32s + q*8 + j] ----
        Frag af[2];
        {
            const int row  = full ? (n0 + r) : min(n0 + r, n_nodes - 1);
            const float* __restrict__ xr = X + ((size_t)row << 6);
#pragma unroll
            for (int s = 0; s < 2; ++s) {
                const float4 f0 = *(const float4*)(xr + 32 * s + q * 8);
                const float4 f1 = *(const float4*)(xr + 32 * s + q * 8 + 4);
                af[s].p[0] = pack2(f0.x, f0.y);
                af[s].p[1] = pack2(f0.z, f0.w);
                af[s].p[2] = pack2(f1.x, f1.y);
                af[s].p[3] = pack2(f1.z, f1.w);
            }
        }

        // ---- 8 MFMA: acc[ft] = sum_s A_s * B[ft][s] ----
        f32x4 acc[4];
#pragma unroll
        for (int ft = 0; ft < 4; ++ft) {
            f32x4 z = {0.f, 0.f, 0.f, 0.f};
            acc[ft] = z;
        }
#pragma unroll
        for (int s = 0; s < 2; ++s)
#pragma unroll
            for (int ft = 0; ft < 4; ++ft)
                acc[ft] = __builtin_amdgcn_mfma_f32_16x16x32_bf16(
                              af[s].v, bf[ft][s].v, acc[ft], 0, 0, 0);

        // ---- epilogue: rows q*4+i, col r (+16*ft) ----
        if (full) {
            const float4 dn = *(const float4*)(deg + n0 + 4 * q);
#pragma unroll
            for (int i = 0; i < 4; ++i) {
                const int   node = n0 + 4 * q + i;
                const float d    = (i == 0) ? dn.x : (i == 1) ? dn.y
                                 : (i == 2) ? dn.z : dn.w;
                ushort* yr = Y + ((size_t)node << 6) + r;
#pragma unroll
                for (int ft = 0; ft < 4; ++ft)
                    yr[16 * ft] = (ushort)bf16r(acc[ft][i] * d);
            }
        } else {
#pragma unroll
            for (int i = 0; i < 4; ++i) {
                const int node = n0 + 4 * q + i;
                if (node < n_nodes) {
                    const float d = deg[node];
                    ushort* yr = Y + ((size_t)node << 6) + r;
#pragma unroll
                    for (int ft = 0; ft < 4; ++ft)
                        yr[16 * ft] = (ushort)bf16r(acc[ft][i] * d);
                }
            }
        }
    }
}

// ---------------------------------------------------------------------------
// K2 (round 4 = round 3 with compile fix): 8 nodes per wave, dwordx4 row
// loads. lane = (slot s=lane>>3 -> node, chunk f=lane&7 -> bf16 feats
// [8f,8f+8)). Same compulsory line traffic as gather4 (each 128-B Y row
// fully consumed by the 8 lanes of its slot), but each in-flight load
// instruction covers 8 distinct lines (vs 4) -> 2x outstanding lines per
// wave at equal vmcnt depth, and half the load-issue count. Out stores
// nontemporal (via clang ext-vector f32x4 — HIP float4 is a class type
// that __builtin_nontemporal_store rejects): round-2 WRITE_SIZE was
// 103.5 MB for a 25.6 MB output -> store path churned L2; nt keeps the
// streamed-once output out of L2, leaving more of the 4 MB/XCD for Y.
// Grid 1563 @ (256,8): 6252 waves, exactly 2 groups/wave, fully resident.
// ---------------------------------------------------------------------------
__global__ __launch_bounds__(256, 8)
void gcn_gather8(const ushort* __restrict__ Y, const int* __restrict__ rp,
                 const int* __restrict__ col, const float* __restrict__ deg,
                 float* __restrict__ out, int n_nodes)
{
    const int lane   = threadIdx.x & 63;
    const int s      = lane >> 3;      // node slot 0..7
    const int f      = lane & 7;       // 16-B feature chunk
    const int gwave  = (int)((blockIdx.x * blockDim.x + threadIdx.x) >> 6);
    const int nwaves = (int)((gridDim.x * blockDim.x) >> 6);
    const int ngroups = (n_nodes + 7) >> 3;

    for (int g = gwave; g < ngroups; g += nwaves) {
        const int  n     = g * 8 + s;
        const bool valid = (n < n_nodes);
        const int  rpn   = valid ? rp[n]     : 0;
        const int  rpe   = valid ? rp[n + 1] : 0;
        const int  dcnt  = rpe - rpn;

        const bool ok = !valid || (dcnt == 16 && (rpn & 3) == 0);
        if (__ballot(ok) == ~0ull) {
            int idx[16];
            *(int4*)(idx + 0)  = *(const int4*)(col + rpn + 0);
            *(int4*)(idx + 4)  = *(const int4*)(col + rpn + 4);
            *(int4*)(idx + 8)  = *(const int4*)(col + rpn + 8);
            *(int4*)(idx + 12) = *(const int4*)(col + rpn + 12);

            float a0 = 0.f, a1 = 0.f, a2 = 0.f, a3 = 0.f;
            float a4 = 0.f, a5 = 0.f, a6 = 0.f, a7 = 0.f;
#pragma unroll
            for (int j = 0; j < 16; ++j) {
                const uint4 u = *(const uint4*)(Y + ((size_t)idx[j] << 6) + (f << 3));
                a0 += __uint_as_float(u.x << 16);
                a1 += __uint_as_float(u.x & 0xffff0000u);
                a2 += __uint_as_float(u.y << 16);
                a3 += __uint_as_float(u.y & 0xffff0000u);
                a4 += __uint_as_float(u.z << 16);
                a5 += __uint_as_float(u.z & 0xffff0000u);
                a6 += __uint_as_float(u.w << 16);
                a7 += __uint_as_float(u.w & 0xffff0000u);
            }
            if (valid) {
                const float dn = deg[n];
                f32x4 v0, v1;
                v0[0] = a0 * dn; v0[1] = a1 * dn; v0[2] = a2 * dn; v0[3] = a3 * dn;
                v1[0] = a4 * dn; v1[1] = a5 * dn; v1[2] = a6 * dn; v1[3] = a7 * dn;
                f32x4* p = (f32x4*)(out + ((size_t)n << 6) + (f << 3));
                __builtin_nontemporal_store(v0, p);
                __builtin_nontemporal_store(v1, p + 1);
            }
        } else if (valid) {
            float a0 = 0.f, a1 = 0.f, a2 = 0.f, a3 = 0.f;
            float a4 = 0.f, a5 = 0.f, a6 = 0.f, a7 = 0.f;
            for (int e = rpn; e < rpe; ++e) {
                const int sj = col[e];
                const uint4 u = *(const uint4*)(Y + ((size_t)sj << 6) + (f << 3));
                a0 += __uint_as_float(u.x << 16);
                a1 += __uint_as_float(u.x & 0xffff0000u);
                a2 += __uint_as_float(u.y << 16);
                a3 += __uint_as_float(u.y & 0xffff0000u);
                a4 += __uint_as_float(u.z << 16);
                a5 += __uint_as_float(u.z & 0xffff0000u);
                a6 += __uint_as_float(u.w << 16);
                a7 += __uint_as_float(u.w & 0xffff0000u);
            }
            const float dn = deg[n];
            f32x4 v0, v1;
            v0[0] = a0 * dn; v0[1] = a1 * dn; v0[2] = a2 * dn; v0[3] = a3 * dn;
            v1[0] = a4 * dn; v1[1] = a5 * dn; v1[2] = a6 * dn; v1[3] = a7 * dn;
            f32x4* p = (f32x4*)(out + ((size_t)n << 6) + (f << 3));
            __builtin_nontemporal_store(v0, p);
            __builtin_nontemporal_store(v1, p + 1);
        }
    }
}

// ---------------------------------------------------------------------------
// Fallback (ws too small): fused fp32 kernel.
// ---------------------------------------------------------------------------
static __device__ __forceinline__ float bcast_f(float v, int l) {
    return __uint_as_float(__builtin_amdgcn_readlane(__float_as_uint(v), l));
}

__global__ __launch_bounds__(256, 4)
void gcn_fused_kernel(const float* __restrict__ X, const float* __restrict__ W,
                      const int* __restrict__ rp, const int* __restrict__ col,
                      const float* __restrict__ deg, float* __restrict__ out,
                      int n_nodes)
{
    const int lane   = threadIdx.x & 63;
    const int gwave  = (int)((blockIdx.x * blockDim.x + threadIdx.x) >> 6);
    const int nwaves = (int)((gridDim.x * blockDim.x) >> 6);

    for (int node = gwave; node < n_nodes; node += nwaves) {
        const int start = rp[node];
        const int end   = rp[node + 1];
        const float di  = deg[node];
        float h = 0.f;

        for (int e0 = start; e0 < end; e0 += 64) {
            const int cnt = min(64, end - e0);
            int   s_  = (lane < cnt) ? col[e0 + lane] : 0;
            float nm_ = (lane < cnt) ? di * deg[s_] : 0.f;
            for (int j = 0; j < cnt; ++j) {
                const int   sj = __builtin_amdgcn_readlane(s_, j);
                const float nj = bcast_f(nm_, j);
                h = fmaf(nj, X[(size_t)sj * D + lane], h);
            }
        }

        float c0 = 0.f, c1 = 0.f, c2 = 0.f, c3 = 0.f;
#pragma unroll
        for (int l = 0; l < D; l += 4) {
            c0 = fmaf(bcast_f(h, l + 0), W[(l + 0) * D + lane], c0);
            c1 = fmaf(bcast_f(h, l + 1), W[(l + 1) * D + lane], c1);
            c2 = fmaf(bcast_f(h, l + 2), W[(l + 2) * D + lane], c2);
            c3 = fmaf(bcast_f(h, l + 3), W[(l + 3) * D + lane], c3);
        }
        out[(size_t)node * D + lane] = (c0 + c1) + (c2 + c3);
    }
}

extern "C" void kernel_launch(void* const* d_in, const int* in_sizes, int n_in,
                              void* d_out, int out_size, void* d_ws, size_t ws_size,
                              hipStream_t stream) {
    const float* X   = (const float*)d_in[0];
    const float* W   = (const float*)d_in[1];
    const int*   rp  = (const int*)d_in[2];
    const int*   col = (const int*)d_in[3];
    const float* deg = (const float*)d_in[4];
    float* out = (float*)d_out;

    const int n_nodes = in_sizes[4];   // degrees: one per node
    const size_t y_bytes = (size_t)n_nodes * D * sizeof(ushort);

    if (ws_size >= y_bytes) {
        ushort* Y = (ushort*)d_ws;
        const int nstrips = (n_nodes + 15) / 16;
        // Round-0 proven K1 config: 768 blocks = 3/CU at (256,4).
        gcn_xw_mfma<<<768, 256, 0, stream>>>(X, W, deg, Y, n_nodes, nstrips);

        // 1563 blocks @ (256,8): 6252 waves, exactly 2 groups of 8 nodes
        // per wave, fully resident and balanced.
        const int ngroups = (n_nodes + 7) >> 3;
        int nb2 = (ngroups + 7) / 8;               // ceil(groups / (4 waves * 2))
        if (nb2 < 1) nb2 = 1;
        gcn_gather8<<<nb2, 256, 0, stream>>>(Y, rp, col, deg, out, n_nodes);
    } else {
        gcn_fused_kernel<<<1024, 256, 0, stream>>>(X, W, rp, col, deg, out, n_nodes);
    }
}

// Round 5
// 117.133 us; speedup vs baseline: 1.8506x; 1.2338x over previous
//
#include <hip/hip_runtime.h>
#include <hip/hip_bf16.h>

#define D 64

typedef __attribute__((ext_vector_type(8))) short bf16x8;
typedef __attribute__((ext_vector_type(4))) float f32x4;

// POD fragment: only trivially-copyable members (bf16 pairs kept as uint).
union Frag {
    bf16x8 v;
    unsigned int p[4];   // each = two packed bf16
    ushort u[8];
};

static __device__ __forceinline__ unsigned int bf16r(float f) {
    const unsigned int u = __float_as_uint(f);
    return (u + 0x7fffu + ((u >> 16) & 1u)) >> 16;   // RNE fp32->bf16
}

static __device__ __forceinline__ unsigned int pack2(float a, float b) {
    return bf16r(a) | (bf16r(b) << 16);              // [lo=a, hi=b]
}

// ---------------------------------------------------------------------------
// K1 (round 5): Y = bf16( deg ⊙ (X @ W) ) — MFMA, OPERANDS SWAPPED.
// K1 measured ~37 us in every config (rounds 1/2/4) vs a 6.4 us BW floor;
// the never-varied suspect is the epilogue's 16 scalar 2-B stores per lane
// (old C layout: col=lane&15 spread adjacent output cols across lanes).
// Swap: acc[ft] = mfma(bf[ft][s], af[s]) computes Z = W^T X^T. The A/B
// fragments are bit-identical to the ones we already build (bf holds
// W^T[16ft+r][32s+8q+j], af holds X^T[32s+8q+j][n0+r]); only the C/D
// mapping flips: col = lane&15 = NODE (n0+r), row = 4q+i = FEATURE
// (c = 16ft+4q+i). Each lane owns one node and 4 consecutive features per
// fragment -> 4x dwordx2 stores/lane (was 16x 2-B), one scalar deg/lane.
// Launch config unchanged from round 0: 768 blocks, (256,4) — the only
// knob that is proven safe.
// ---------------------------------------------------------------------------
__global__ __launch_bounds__(256, 4)
void gcn_xw_mfma(const float* __restrict__ X, const float* __restrict__ W,
                 const float* __restrict__ deg, ushort* __restrict__ Y,
                 int n_nodes, int nstrips)
{
    __shared__ ushort Wt[64][72];      // Wt[c][k] = bf16(W[k][c])

    const int t    = threadIdx.x;
    const int lane = t & 63;
    const int q    = lane >> 4;        // quad 0..3
    const int r    = lane & 15;        // node-in-strip (after swap)

    // ---- cooperative W -> LDS (transposed, bf16); fully coalesced ----
    {
        const float4* __restrict__ W4 = (const float4*)W;
#pragma unroll
        for (int m = 0; m < 4; ++m) {
            const float4 v = W4[t + 256 * m];
            const int idx0 = 4 * (t + 256 * m);   // flat element idx of v.x
            const int k = idx0 >> 6;              // W row
            const int c = idx0 & 63;              // W col of v.x
            Wt[c + 0][k] = (ushort)bf16r(v.x);
            Wt[c + 1][k] = (ushort)bf16r(v.y);
            Wt[c + 2][k] = (ushort)bf16r(v.z);
            Wt[c + 3][k] = (ushort)bf16r(v.w);
        }
    }
    __syncthreads();

    // ---- W^T fragments (MFMA A-operand after swap):
    //      bf[ft][s].u[j] = W^T[16ft+r][32s+8q+j] = W[32s+8q+j][16ft+r] ----
    Frag bf[4][2];
#pragma unroll
    for (int ft = 0; ft < 4; ++ft)
#pragma unroll
        for (int s = 0; s < 2; ++s)
            bf[ft][s].v = *(const bf16x8*)&Wt[16 * ft + r][32 * s + 8 * q];

    const int wid = blockIdx.x * 4 + (t >> 6);
    const int nw  = gridDim.x * 4;

    for (int strip = wid; strip < nstrips; strip += nw) {
        const int n0 = strip * 16;
        const bool full = (n0 + 16 <= n_nodes);

        // ---- X^T fragments (MFMA B-operand): af[s].u[j] = X[n0+r][32s+8q+j]
        Frag af[2];
        {
            const int row  = full ? (n0 + r) : min(n0 + r, n_nodes - 1);
            const float* __restrict__ xr = X + ((size_t)row << 6);
#pragma unroll
            for (int s = 0; s < 2; ++s) {
                const float4 f0 = *(const float4*)(xr + 32 * s + q * 8);
                const float4 f1 = *(const float4*)(xr + 32 * s + q * 8 + 4);
                af[s].p[0] = pack2(f0.x, f0.y);
                af[s].p[1] = pack2(f0.z, f0.w);
                af[s].p[2] = pack2(f1.x, f1.y);
                af[s].p[3] = pack2(f1.z, f1.w);
            }
        }

        // ---- 8 MFMA, SWAPPED: acc[ft] = sum_s (W^T frag ft) * (X^T frag) --
        f32x4 acc[4];
#pragma unroll
        for (int ft = 0; ft < 4; ++ft) {
            f32x4 z = {0.f, 0.f, 0.f, 0.f};
            acc[ft] = z;
        }
#pragma unroll
        for (int s = 0; s < 2; ++s)
#pragma unroll
            for (int ft = 0; ft < 4; ++ft)
                acc[ft] = __builtin_amdgcn_mfma_f32_16x16x32_bf16(
                              bf[ft][s].v, af[s].v, acc[ft], 0, 0, 0);

        // ---- epilogue: lane owns node n0+r; acc[ft][i] = Y[node][16ft+4q+i]
        const int node = n0 + r;
        if (full || node < n_nodes) {
            const float d = deg[node];
            ushort* yr = Y + ((size_t)node << 6) + 4 * q;
#pragma unroll
            for (int ft = 0; ft < 4; ++ft) {
                uint2 w;
                w.x = pack2(acc[ft][0] * d, acc[ft][1] * d);
                w.y = pack2(acc[ft][2] * d, acc[ft][3] * d);
                *(uint2*)(yr + 16 * ft) = w;
            }
        }
    }
}

// ---------------------------------------------------------------------------
// K2: out[i][:] = deg[i] * sum_e Y[col[e]][:] — ROUND-0 PROVEN VERSION,
// RESTORED EXACTLY: 4 nodes/wave, dwordx2 row loads, (256,4), 2048 blocks.
// Round 2/4 showed launch_bounds(256,8) cut VGPR_Count to 32 and the
// compiler serialized the 16-load MLP chain: 34 -> 58-62 us. The (256,4)
// budget (128 VGPR) keeps all 16 row loads in flight. ~34 us measured
// (inferred round 0). Do not touch launch config or reg budget.
// ---------------------------------------------------------------------------
__global__ __launch_bounds__(256, 4)
void gcn_gather4(const ushort* __restrict__ Y, const int* __restrict__ rp,
                 const int* __restrict__ col, const float* __restrict__ deg,
                 float* __restrict__ out, int n_nodes)
{
    const int lane   = threadIdx.x & 63;
    const int s      = lane >> 4;
    const int f      = lane & 15;
    const int gwave  = (int)((blockIdx.x * blockDim.x + threadIdx.x) >> 6);
    const int nwaves = (int)((gridDim.x * blockDim.x) >> 6);
    const int ngroups = (n_nodes + 3) >> 2;

    for (int g = gwave; g < ngroups; g += nwaves) {
        const int  n     = g * 4 + s;
        const bool valid = (n < n_nodes);
        const int  rpn   = valid ? rp[n]     : 0;
        const int  rpe   = valid ? rp[n + 1] : 0;
        const int  dcnt  = rpe - rpn;

        const bool ok = !valid || (dcnt == 16 && (rpn & 3) == 0);
        if (__ballot(ok) == ~0ull) {
            int idx[16];
            *(int4*)(idx + 0)  = *(const int4*)(col + rpn + 0);
            *(int4*)(idx + 4)  = *(const int4*)(col + rpn + 4);
            *(int4*)(idx + 8)  = *(const int4*)(col + rpn + 8);
            *(int4*)(idx + 12) = *(const int4*)(col + rpn + 12);

            float a0 = 0.f, a1 = 0.f, a2 = 0.f, a3 = 0.f;
#pragma unroll
            for (int j = 0; j < 16; ++j) {
                const uint2 u = *(const uint2*)(Y + ((size_t)idx[j] << 6) + (f << 2));
                a0 += __uint_as_float(u.x << 16);
                a1 += __uint_as_float(u.x & 0xffff0000u);
                a2 += __uint_as_float(u.y << 16);
                a3 += __uint_as_float(u.y & 0xffff0000u);
            }
            if (valid) {
                const float dn = deg[n];
                float4 v;
                v.x = a0 * dn; v.y = a1 * dn; v.z = a2 * dn; v.w = a3 * dn;
                *(float4*)(out + (size_t)n * D + f * 4) = v;
            }
        } else if (valid) {
            float a0 = 0.f, a1 = 0.f, a2 = 0.f, a3 = 0.f;
            for (int e = rpn; e < rpe; ++e) {
                const int sj = col[e];
                const uint2 u = *(const uint2*)(Y + ((size_t)sj << 6) + (f << 2));
                a0 += __uint_as_float(u.x << 16);
                a1 += __uint_as_float(u.x & 0xffff0000u);
                a2 += __uint_as_float(u.y << 16);
                a3 += __uint_as_float(u.y & 0xffff0000u);
            }
            const float dn = deg[n];
            float4 v;
            v.x = a0 * dn; v.y = a1 * dn; v.z = a2 * dn; v.w = a3 * dn;
            *(float4*)(out + (size_t)n * D + f * 4) = v;
        }
    }
}

// ---------------------------------------------------------------------------
// Fallback (ws too small): fused fp32 kernel.
// ---------------------------------------------------------------------------
static __device__ __forceinline__ float bcast_f(float v, int l) {
    return __uint_as_float(__builtin_amdgcn_readlane(__float_as_uint(v), l));
}

__global__ __launch_bounds__(256, 4)
void gcn_fused_kernel(const float* __restrict__ X, const float* __restrict__ W,
                      const int* __restrict__ rp, const int* __restrict__ col,
                      const float* __restrict__ deg, float* __restrict__ out,
                      int n_nodes)
{
    const int lane   = threadIdx.x & 63;
    const int gwave  = (int)((blockIdx.x * blockDim.x + threadIdx.x) >> 6);
    const int nwaves = (int)((gridDim.x * blockDim.x) >> 6);

    for (int node = gwave; node < n_nodes; node += nwaves) {
        const int start = rp[node];
        const int end   = rp[node + 1];
        const float di  = deg[node];
        float h = 0.f;

        for (int e0 = start; e0 < end; e0 += 64) {
            const int cnt = min(64, end - e0);
            int   s_  = (lane < cnt) ? col[e0 + lane] : 0;
            float nm_ = (lane < cnt) ? di * deg[s_] : 0.f;
            for (int j = 0; j < cnt; ++j) {
                const int   sj = __builtin_amdgcn_readlane(s_, j);
                const float nj = bcast_f(nm_, j);
                h = fmaf(nj, X[(size_t)sj * D + lane], h);
            }
        }

        float c0 = 0.f, c1 = 0.f, c2 = 0.f, c3 = 0.f;
#pragma unroll
        for (int l = 0; l < D; l += 4) {
            c0 = fmaf(bcast_f(h, l + 0), W[(l + 0) * D + lane], c0);
            c1 = fmaf(bcast_f(h, l + 1), W[(l + 1) * D + lane], c1);
            c2 = fmaf(bcast_f(h, l + 2), W[(l + 2) * D + lane], c2);
            c3 = fmaf(bcast_f(h, l + 3), W[(l + 3) * D + lane], c3);
        }
        out[(size_t)node * D + lane] = (c0 + c1) + (c2 + c3);
    }
}

extern "C" void kernel_launch(void* const* d_in, const int* in_sizes, int n_in,
                              void* d_out, int out_size, void* d_ws, size_t ws_size,
                              hipStream_t stream) {
    const float* X   = (const float*)d_in[0];
    const float* W   = (const float*)d_in[1];
    const int*   rp  = (const int*)d_in[2];
    const int*   col = (const int*)d_in[3];
    const float* deg = (const float*)d_in[4];
    float* out = (float*)d_out;

    const int n_nodes = in_sizes[4];   // degrees: one per node
    const size_t y_bytes = (size_t)n_nodes * D * sizeof(ushort);

    if (ws_size >= y_bytes) {
        ushort* Y = (ushort*)d_ws;
        const int nstrips = (n_nodes + 15) / 16;
        // Round-0 proven K1 launch: 768 blocks = 3/CU at (256,4).
        gcn_xw_mfma<<<768, 256, 0, stream>>>(X, W, deg, Y, n_nodes, nstrips);
        // Round-0 proven K2 launch: 2048 blocks at (256,4).
        gcn_gather4<<<2048, 256, 0, stream>>>(Y, rp, col, deg, out, n_nodes);
    } else {
        gcn_fused_kernel<<<1024, 256, 0, stream>>>(X, W, rp, col, deg, out, n_nodes);
    }
}

// Round 7
// 114.589 us; speedup vs baseline: 1.8917x; 1.0222x over previous
//
#include <hip/hip_runtime.h>
#include <hip/hip_bf16.h>

#define D 64

typedef __attribute__((ext_vector_type(8))) short bf16x8;
typedef __attribute__((ext_vector_type(4))) float f32x4;

// POD fragment: only trivially-copyable members (bf16 pairs kept as uint).
union Frag {
    bf16x8 v;
    unsigned int p[4];   // each = two packed bf16
    ushort u[8];
};

static __device__ __forceinline__ unsigned int bf16r(float f) {
    const unsigned int u = __float_as_uint(f);
    return (u + 0x7fffu + ((u >> 16) & 1u)) >> 16;   // RNE fp32->bf16
}

static __device__ __forceinline__ unsigned int pack2(float a, float b) {
    return bf16r(a) | (bf16r(b) << 16);              // [lo=a, hi=b]
}

// ---------------------------------------------------------------------------
// K1: Y = bf16( deg ⊙ (X @ W) ) — MFMA, swapped operands (round 5, neutral
// but strictly fewer epilogue instructions; C layout: col=lane&15=node,
// row=4q+i=feature -> 4x dwordx2 stores/lane).
// Grid 1563 @ (256,4) — 1 strip/wave. Measured: round 1 ran K1 at this
// exact grid/bounds and was 3 us faster than 768 blocks (round 4) with
// the same kernel body. (Earlier 'K1 = 37us' readings were fixed
// per-iteration harness overhead — dozens of reset() memsets + launch
// gaps — misattributed to K1; true K1 ~ 10-14 us.)
// ---------------------------------------------------------------------------
__global__ __launch_bounds__(256, 4)
void gcn_xw_mfma(const float* __restrict__ X, const float* __restrict__ W,
                 const float* __restrict__ deg, ushort* __restrict__ Y,
                 int n_nodes, int nstrips)
{
    __shared__ ushort Wt[64][72];      // Wt[c][k] = bf16(W[k][c])

    const int t    = threadIdx.x;
    const int lane = t & 63;
    const int q    = lane >> 4;        // quad 0..3
    const int r    = lane & 15;        // node-in-strip (after swap)

    // ---- cooperative W -> LDS (transposed, bf16); fully coalesced ----
    {
        const float4* __restrict__ W4 = (const float4*)W;
#pragma unroll
        for (int m = 0; m < 4; ++m) {
            const float4 v = W4[t + 256 * m];
            const int idx0 = 4 * (t + 256 * m);   // flat element idx of v.x
            const int k = idx0 >> 6;              // W row
            const int c = idx0 & 63;              // W col of v.x
            Wt[c + 0][k] = (ushort)bf16r(v.x);
            Wt[c + 1][k] = (ushort)bf16r(v.y);
            Wt[c + 2][k] = (ushort)bf16r(v.z);
            Wt[c + 3][k] = (ushort)bf16r(v.w);
        }
    }
    __syncthreads();

    // ---- W^T fragments (MFMA A-operand after swap):
    //      bf[ft][s].u[j] = W^T[16ft+r][32s+8q+j] = W[32s+8q+j][16ft+r] ----
    Frag bf[4][2];
#pragma unroll
    for (int ft = 0; ft < 4; ++ft)
#pragma unroll
        for (int s = 0; s < 2; ++s)
            bf[ft][s].v = *(const bf16x8*)&Wt[16 * ft + r][32 * s + 8 * q];

    const int wid = blockIdx.x * 4 + (t >> 6);
    const int nw  = gridDim.x * 4;

    for (int strip = wid; strip < nstrips; strip += nw) {
        const int n0 = strip * 16;
        const bool full = (n0 + 16 <= n_nodes);

        // ---- X^T fragments (MFMA B-operand): af[s].u[j] = X[n0+r][32s+8q+j]
        Frag af[2];
        {
            const int row  = full ? (n0 + r) : min(n0 + r, n_nodes - 1);
            const float* __restrict__ xr = X + ((size_t)row << 6);
#pragma unroll
            for (int s = 0; s < 2; ++s) {
                const float4 f0 = *(const float4*)(xr + 32 * s + q * 8);
                const float4 f1 = *(const float4*)(xr + 32 * s + q * 8 + 4);
                af[s].p[0] = pack2(f0.x, f0.y);
                af[s].p[1] = pack2(f0.z, f0.w);
                af[s].p[2] = pack2(f1.x, f1.y);
                af[s].p[3] = pack2(f1.z, f1.w);
            }
        }

        // ---- 8 MFMA, swapped: acc[ft] = sum_s (W^T frag ft) * (X^T frag) --
        f32x4 acc[4];
#pragma unroll
        for (int ft = 0; ft < 4; ++ft) {
            f32x4 z = {0.f, 0.f, 0.f, 0.f};
            acc[ft] = z;
        }
#pragma unroll
        for (int s = 0; s < 2; ++s)
#pragma unroll
            for (int ft = 0; ft < 4; ++ft)
                acc[ft] = __builtin_amdgcn_mfma_f32_16x16x32_bf16(
                              bf[ft][s].v, af[s].v, acc[ft], 0, 0, 0);

        // ---- epilogue: lane owns node n0+r; acc[ft][i] = Y[node][16ft+4q+i]
        const int node = n0 + r;
        if (full || node < n_nodes) {
            const float d = deg[node];
            ushort* yr = Y + ((size_t)node << 6) + 4 * q;
#pragma unroll
            for (int ft = 0; ft < 4; ++ft) {
                uint2 w;
                w.x = pack2(acc[ft][0] * d, acc[ft][1] * d);
                w.y = pack2(acc[ft][2] * d, acc[ft][3] * d);
                *(uint2*)(yr + 16 * ft) = w;
            }
        }
    }
}

// ---------------------------------------------------------------------------
// K2: gather8 at the (256,4) register budget — the untested cell.
// 8 nodes/wave, lane = (slot s=lane>>3, chunk f=lane&7 -> 16 B of the row).
// 16 independent dwordx4 row loads per lane (256 B/lane in flight, 2x
// gather4) at 128-VGPR budget so the whole MLP chain stays in flight
// (round 2/4 showed the (256,8)/64-VGPR bound serialized it: 58-62 us).
// nt stores (proven round 4: WRITE 103->99 MB) keep the streamed-once
// output from churning L2's Y window. Grid 2048 @ (256,4): two clean
// 1024-block batches.
// ---------------------------------------------------------------------------
__global__ __launch_bounds__(256, 4)
void gcn_gather8(const ushort* __restrict__ Y, const int* __restrict__ rp,
                 const int* __restrict__ col, const float* __restrict__ deg,
                 float* __restrict__ out, int n_nodes)
{
    const int lane   = threadIdx.x & 63;
    const int s      = lane >> 3;      // node slot 0..7
    const int f      = lane & 7;       // 16-B feature chunk
    const int gwave  = (int)((blockIdx.x * blockDim.x + threadIdx.x) >> 6);
    const int nwaves = (int)((gridDim.x * blockDim.x) >> 6);
    const int ngroups = (n_nodes + 7) >> 3;

    for (int g = gwave; g < ngroups; g += nwaves) {
        const int  n     = g * 8 + s;
        const bool valid = (n < n_nodes);
        const int  rpn   = valid ? rp[n]     : 0;
        const int  rpe   = valid ? rp[n + 1] : 0;
        const int  dcnt  = rpe - rpn;

        const bool ok = !valid || (dcnt == 16 && (rpn & 3) == 0);
        if (__ballot(ok) == ~0ull) {
            int idx[16];
            *(int4*)(idx + 0)  = *(const int4*)(col + rpn + 0);
            *(int4*)(idx + 4)  = *(const int4*)(col + rpn + 4);
            *(int4*)(idx + 8)  = *(const int4*)(col + rpn + 8);
            *(int4*)(idx + 12) = *(const int4*)(col + rpn + 12);

            float a0 = 0.f, a1 = 0.f, a2 = 0.f, a3 = 0.f;
            float a4 = 0.f, a5 = 0.f, a6 = 0.f, a7 = 0.f;
#pragma unroll
            for (int j = 0; j < 16; ++j) {
                const uint4 u = *(const uint4*)(Y + ((size_t)idx[j] << 6) + (f << 3));
                a0 += __uint_as_float(u.x << 16);
                a1 += __uint_as_float(u.x & 0xffff0000u);
                a2 += __uint_as_float(u.y << 16);
                a3 += __uint_as_float(u.y & 0xffff0000u);
                a4 += __uint_as_float(u.z << 16);
                a5 += __uint_as_float(u.z & 0xffff0000u);
                a6 += __uint_as_float(u.w << 16);
                a7 += __uint_as_float(u.w & 0xffff0000u);
            }
            if (valid) {
                const float dn = deg[n];
                f32x4 v0, v1;
                v0[0] = a0 * dn; v0[1] = a1 * dn; v0[2] = a2 * dn; v0[3] = a3 * dn;
                v1[0] = a4 * dn; v1[1] = a5 * dn; v1[2] = a6 * dn; v1[3] = a7 * dn;
                f32x4* p = (f32x4*)(out + ((size_t)n << 6) + (f << 3));
                __builtin_nontemporal_store(v0, p);
                __builtin_nontemporal_store(v1, p + 1);
            }
        } else if (valid) {
            float a0 = 0.f, a1 = 0.f, a2 = 0.f, a3 = 0.f;
            float a4 = 0.f, a5 = 0.f, a6 = 0.f, a7 = 0.f;
            for (int e = rpn; e < rpe; ++e) {
                const int sj = col[e];
                const uint4 u = *(const uint4*)(Y + ((size_t)sj << 6) + (f << 3));
                a0 += __uint_as_float(u.x << 16);
                a1 += __uint_as_float(u.x & 0xffff0000u);
                a2 += __uint_as_float(u.y << 16);
                a3 += __uint_as_float(u.y & 0xffff0000u);
                a4 += __uint_as_float(u.z << 16);
                a5 += __uint_as_float(u.z & 0xffff0000u);
                a6 += __uint_as_float(u.w << 16);
                a7 += __uint_as_float(u.w & 0xffff0000u);
            }
            const float dn = deg[n];
            f32x4 v0, v1;
            v0[0] = a0 * dn; v0[1] = a1 * dn; v0[2] = a2 * dn; v0[3] = a3 * dn;
            v1[0] = a4 * dn; v1[1] = a5 * dn; v1[2] = a6 * dn; v1[3] = a7 * dn;
            f32x4* p = (f32x4*)(out + ((size_t)n << 6) + (f << 3));
            __builtin_nontemporal_store(v0, p);
            __builtin_nontemporal_store(v1, p + 1);
        }
    }
}

// ---------------------------------------------------------------------------
// Fallback (ws too small): fused fp32 kernel.
// ---------------------------------------------------------------------------
static __device__ __forceinline__ float bcast_f(float v, int l) {
    return __uint_as_float(__builtin_amdgcn_readlane(__float_as_uint(v), l));
}

__global__ __launch_bounds__(256, 4)
void gcn_fused_kernel(const float* __restrict__ X, const float* __restrict__ W,
                      const int* __restrict__ rp, const int* __restrict__ col,
                      const float* __restrict__ deg, float* __restrict__ out,
                      int n_nodes)
{
    const int lane   = threadIdx.x & 63;
    const int gwave  = (int)((blockIdx.x * blockDim.x + threadIdx.x) >> 6);
    const int nwaves = (int)((gridDim.x * blockDim.x) >> 6);

    for (int node = gwave; node < n_nodes; node += nwaves) {
        const int start = rp[node];
        const int end   = rp[node + 1];
        const float di  = deg[node];
        float h = 0.f;

        for (int e0 = start; e0 < end; e0 += 64) {
            const int cnt = min(64, end - e0);
            int   s_  = (lane < cnt) ? col[e0 + lane] : 0;
            float nm_ = (lane < cnt) ? di * deg[s_] : 0.f;
            for (int j = 0; j < cnt; ++j) {
                const int   sj = __builtin_amdgcn_readlane(s_, j);
                const float nj = bcast_f(nm_, j);
                h = fmaf(nj, X[(size_t)sj * D + lane], h);
            }
        }

        float c0 = 0.f, c1 = 0.f, c2 = 0.f, c3 = 0.f;
#pragma unroll
        for (int l = 0; l < D; l += 4) {
            c0 = fmaf(bcast_f(h, l + 0), W[(l + 0) * D + lane], c0);
            c1 = fmaf(bcast_f(h, l + 1), W[(l + 1) * D + lane], c1);
            c2 = fmaf(bcast_f(h, l + 2), W[(l + 2) * D + lane], c2);
            c3 = fmaf(bcast_f(h, l + 3), W[(l + 3) * D + lane], c3);
        }
        out[(size_t)node * D + lane] = (c0 + c1) + (c2 + c3);
    }
}

extern "C" void kernel_launch(void* const* d_in, const int* in_sizes, int n_in,
                              void* d_out, int out_size, void* d_ws, size_t ws_size,
                              hipStream_t stream) {
    const float* X   = (const float*)d_in[0];
    const float* W   = (const float*)d_in[1];
    const int*   rp  = (const int*)d_in[2];
    const int*   col = (const int*)d_in[3];
    const float* deg = (const float*)d_in[4];
    float* out = (float*)d_out;

    const int n_nodes = in_sizes[4];   // degrees: one per node
    const size_t y_bytes = (size_t)n_nodes * D * sizeof(ushort);

    if (ws_size >= y_bytes) {
        ushort* Y = (ushort*)d_ws;
        const int nstrips = (n_nodes + 15) / 16;
        // 1563 blocks @ (256,4): 1 strip/wave — measured 3 us faster than
        // 768 blocks (round 1 vs round 4, same kernel body & bounds).
        int nb1 = (nstrips + 3) / 4;
        if (nb1 < 1) nb1 = 1;
        gcn_xw_mfma<<<nb1, 256, 0, stream>>>(X, W, deg, Y, n_nodes, nstrips);
        // gather8 at full register budget: 2048 blocks @ (256,4).
        gcn_gather8<<<2048, 256, 0, stream>>>(Y, rp, col, deg, out, n_nodes);
    } else {
        gcn_fused_kernel<<<1024, 256, 0, stream>>>(X, W, rp, col, deg, out, n_nodes);
    }
}